// Round 1
// baseline (150.305 us; speedup 1.0000x reference)
//
#include <hip/hip_runtime.h>
#include <hip/hip_bf16.h>

// FlowNetC correlation via bf16 MFMA, fp32 accumulate.
// out[b, r*21+dx, y, x] = (1/256) * sum_c in1[b,c,y,x] * in2[b,c, y+2r-20, x+2dx-20]
//
// Round-5 structure (round-4 + single-barrier double-buffered epilogue):
//  1) conv_in2 prepass: in2 fp32 -> in2t bf16 in FRAG-NATIVE chunks
//     [b][y][c8=c/8][x][c%8]: a 16x16x32-MFMA B-fragment (8 consecutive c at one x)
//     is ONE 16-B contiguous global load. 16.8 MB in d_ws.
//  2) corr_mfma: block = (b, y-pair {y0, y0+2}), 1024 thr (16 waves), 1 block/CU.
//     Wave w: tile (m = w&3, n = m + (w>>2)) -- exactly the 16 needed band tiles.
//     A-frags for BOTH y's live in VGPRs (64 regs, built once, reused 22 iters).
//     Per iter i (in2 row yy = y0-20+2i): 8 dwordx4 B-loads straight from L2
//     (b = blk&7 pins batch to one XCD; 2.1 MB slice fits its 4 MB L2), each
//     wfrag feeds 2 MFMAs (y-pair reuse halves W traffic/MFMA). No B-LDS at all.
//     Epilogue: diagonal gather via slds[i&1] (double buffer) -> coalesced
//     stores; ONE barrier per iteration (iter i+1 writes the other buffer, so
//     store(i) reads race nothing; buffer reuse at i+2 is fenced by sync(i+1)).

typedef short    bf16x8 __attribute__((ext_vector_type(8)));
typedef float    f32x4  __attribute__((ext_vector_type(4)));

constexpr int CSTRIDE = 64 * 64;        // fp32 channel plane
constexpr int BSTRIDE = 256 * CSTRIDE;  // fp32 batch

union BF2 { __hip_bfloat162 h; unsigned u; };
union BF1 { __hip_bfloat16 h; unsigned short u; };

__device__ inline unsigned pack_bf2(float lo, float hi) {
    BF2 cv;
    cv.h = __float22bfloat162_rn(make_float2(lo, hi));
    return cv.u;
}

__device__ __align__(16) const uint4 ZERO16 = {0u, 0u, 0u, 0u};

// ---------------- prepass: in2 -> bf16 frag-native chunks ----------------
__global__ __launch_bounds__(256)
void conv_in2(const float* __restrict__ in2, unsigned* __restrict__ out_dw)
{
    __shared__ unsigned short lt[64 * 66];   // [x][c_local], 66 keeps banks spread
    const int tid = threadIdx.x;
    const int b = blockIdx.x & 7;
    const int y = blockIdx.x >> 3;
    const float* src = in2 + b * BSTRIDE + y * 64;            // + c*4096 + x
    unsigned* odw = out_dw + (b * 64 + y) * 8192;             // 32 KB per (b,y)

    for (int c0 = 0; c0 < 256; c0 += 64) {
        __syncthreads();
#pragma unroll
        for (int it = 0; it < 16; ++it) {
            const int c = it * 4 + (tid >> 6);
            const int x = tid & 63;
            BF1 cv; cv.h = __float2bfloat16(src[(c0 + c) * CSTRIDE + x]);
            lt[x * 66 + c] = cv.u;
        }
        __syncthreads();
        const unsigned* ldw = reinterpret_cast<const unsigned*>(lt);
#pragma unroll
        for (int it = 0; it < 8; ++it) {
            const int d   = tid + 256 * it;   // 0..2047 dwords this c0-chunk
            const int c8g = d >> 8;           // 0..7   (local c8)
            const int x   = (d >> 2) & 63;
            const int cd2 = d & 3;            // dword within 16-B chunk
            // dest chunk (c8 = c0/8 + c8g, x): 4 dwords; writes are contiguous
            odw[((c0 >> 3) + c8g) * 256 + x * 4 + cd2] = ldw[x * 33 + c8g * 4 + cd2];
        }
    }
}

// ---------------- main correlation kernel ----------------
__global__ __launch_bounds__(1024, 4)
void corr_mfma(const float* __restrict__ in1,
               const uint4* __restrict__ in2t,
               float* __restrict__ out)
{
    __shared__ float slds[2][2][21 * 65];   // [iter&1][y-half], 21.8 KB

    const int tid  = threadIdx.x;
    const int lane = tid & 63;
    const int w    = tid >> 6;          // wave 0..15
    const int cl   = lane & 15;         // MFMA m/n lane index
    const int q    = lane >> 4;         // MFMA quad
    const int m    = w & 3;             // M-tile: gx in [16m, 16m+16)
    const int n    = m + (w >> 2);      // N-tile: col in [16n, 16n+16), n in 0..6
    const int b    = blockIdx.x & 7;    // batch -> XCD affinity
    const int p    = blockIdx.x >> 3;   // 0..31
    const int y0   = 4 * (p >> 1) + (p & 1);   // pair (y0, y0+2), covers all y

    // ---- A fragments for both y's: af[h][k] = in1[b, 32k+8q+j, y0+2h, 16m+cl] ----
    bf16x8 af[2][8];
#pragma unroll
    for (int h = 0; h < 2; ++h) {
        const float* pb = in1 + b * BSTRIDE + (y0 + 2 * h) * 64 + 16 * m + cl
                        + 8 * q * CSTRIDE;
#pragma unroll
        for (int k = 0; k < 8; ++k) {
            const float* pp = pb + 32 * k * CSTRIDE;
            float v[8];
#pragma unroll
            for (int j = 0; j < 8; ++j) v[j] = pp[j * CSTRIDE];
#pragma unroll
            for (int j = 0; j < 4; ++j)
                ((unsigned*)&af[h][k])[j] = pack_bf2(v[2 * j], v[2 * j + 1]);
        }
    }

    const int  x    = 16 * n + cl - 20;              // W col -> in2 x (may be OOB=0)
    const bool xok  = (x >= 0) && (x < 64);
    const int  gcol = 16 * n + cl;

    for (int i = 0; i < 22; ++i) {
        const int  yy      = y0 - 20 + 2 * i;
        const bool compute = (yy >= 0) && (yy < 64);
        const int  ib      = i & 1;

        if (compute) {
            const uint4* src = in2t + (b * 64 + yy) * 2048 + x;   // + (4k+q)*64
            f32x4 acc0 = {0.f, 0.f, 0.f, 0.f};
            f32x4 acc1 = {0.f, 0.f, 0.f, 0.f};
#pragma unroll
            for (int k = 0; k < 8; ++k) {
                const uint4* pk = xok ? (src + (4 * k + q) * 64) : &ZERO16;
                const uint4  wv = *pk;
                const bf16x8 bf = __builtin_bit_cast(bf16x8, wv);
                acc0 = __builtin_amdgcn_mfma_f32_16x16x32_bf16(af[0][k], bf, acc0, 0, 0, 0);
                acc1 = __builtin_amdgcn_mfma_f32_16x16x32_bf16(af[1][k], bf, acc1, 0, 0, 0);
            }
            // diagonal gather: D[row=4q+i4][col=cl]; gx = 16m+4q+i4, d2 = gcol-gx
#pragma unroll
            for (int i4 = 0; i4 < 4; ++i4) {
                const int gx = 16 * m + 4 * q + i4;
                const int d2 = gcol - gx;
                if (d2 >= 0 && d2 <= 40 && !(d2 & 1)) {
                    slds[ib][0][(d2 >> 1) * 65 + gx] = acc0[i4];
                    slds[ib][1][(d2 >> 1) * 65 + gx] = acc1[i4];
                }
            }
        }
        __syncthreads();

        // half0 -> (y0, r=i), half1 -> (y0+2, r=i-1); coalesced stores
        const int r0 = i, r1 = i - 1;
#pragma unroll
        for (int t3 = 0; t3 < 3; ++t3) {
            const int t = tid + 1024 * t3;
            if (t < 2 * 21 * 64) {
                const int h  = (t >= 1344) ? 1 : 0;
                const int u  = t - 1344 * h;
                const int dx = u >> 6, gx = u & 63;
                const int r  = h ? r1 : r0;
                if (r >= 0 && r <= 20) {
                    const float val = compute ? slds[ib][h][dx * 65 + gx] * (1.f / 256.f)
                                              : 0.f;
                    out[((b * 441 + r * 21 + dx) * 64 + y0 + 2 * h) * 64 + gx] = val;
                }
            }
        }
        // no trailing barrier: iter i+1 writes slds[ib^1]; slds[ib] is reused
        // only at iter i+2, which is fenced by the sync inside iter i+1.
    }
}

extern "C" void kernel_launch(void* const* d_in, const int* in_sizes, int n_in,
                              void* d_out, int out_size, void* d_ws, size_t ws_size,
                              hipStream_t stream) {
    const float* in1 = (const float*)d_in[0];
    const float* in2 = (const float*)d_in[1];
    float* out = (float*)d_out;

    conv_in2<<<dim3(512), dim3(256), 0, stream>>>(in2, (unsigned*)d_ws);
    corr_mfma<<<dim3(256), dim3(1024), 0, stream>>>(in1, (const uint4*)d_ws, out);
}